// Round 1
// baseline (7112.341 us; speedup 1.0000x reference)
//
#include <hip/hip_runtime.h>

// Problem dims
#define BB 128
#define LL 64
#define DD 256
#define HH 512
#define NEGC (-1e9f)

// ws offsets (in floats)
#define OFF_DENSE   0            // B*L*D   = 2,097,152
#define OFF_ENCOUT  2097152      // B*L*H   = 4,194,304
#define OFF_ENCKEYS 6291456      // B*L*512 = 4,194,304
#define OFF_PTRKEYS 10485760     // B*L*256 = 2,097,152
#define OFF_X       12582912     // B*768   =    98,304  [ctx(512)|dec_in(256)]
#define OFF_HB0     12681216     // B*H
#define OFF_HB1     12746752     // B*H
#define OFF_H0      12812288     // B*H
#define OFF_Q       12877824     // B*512
#define OFF_PQ      12943360     // B*256
#define OFF_WQT     12976128     // 512*512 (s2s_Wq transposed)
#define OFF_MT      13238272     // 256*512 (W_out^T @ ptr_Wq, transposed to [a][h])
#define OFF_BQ      13369344     // 256
#define OFF_SMASK   13369600     // B*L ints
// total ~13,377,792 floats = ~53.5 MB

__device__ __forceinline__ float fast_tanh(float x) {
  float e = __expf(2.0f * x);
  return 1.0f - 2.0f / (e + 1.0f);   // safe at +-inf
}
__device__ __forceinline__ float sigmoidf_(float x) {
  return 1.0f / (1.0f + __expf(-x));
}
__device__ __forceinline__ float wsum(float v) {
#pragma unroll
  for (int o = 32; o > 0; o >>= 1) v += __shfl_xor(v, o);
  return v;
}

#define D4(acc) fmaf(xv.x, w.x, fmaf(xv.y, w.y, fmaf(xv.z, w.z, fmaf(xv.w, w.w, acc))))

// ---------------- setup kernels ----------------

// dense_inputs = inputs @ W_in.T + b_in ; zero hbuf0 ; step_mask = 1
__global__ __launch_bounds__(256)
void k_init(const float* __restrict__ inp, const float* __restrict__ W_in,
            const float* __restrict__ b_in, float* __restrict__ dense,
            float* __restrict__ hb0, int* __restrict__ smask) {
  int idx = blockIdx.x * 256 + threadIdx.x;
  if (idx < BB * LL * DD) {
    int bl = idx >> 8, d = idx & 255;
    dense[idx] = fmaf(inp[bl * 2], W_in[d * 2], fmaf(inp[bl * 2 + 1], W_in[d * 2 + 1], b_in[d]));
  } else if (idx < BB * LL * DD + BB * HH) {
    hb0[idx - BB * LL * DD] = 0.f;
  } else if (idx < BB * LL * DD + BB * HH + BB * LL) {
    smask[idx - BB * LL * DD - BB * HH] = 1;
  }
}

// Wqt[a][h] = s2s_Wq[h][a]
__global__ __launch_bounds__(256)
void k_tr(const float* __restrict__ Wq, float* __restrict__ Wqt) {
  int idx = blockIdx.x * 256 + threadIdx.x;   // 262144 exact
  int h = idx >> 9, a = idx & 511;
  Wqt[a * 512 + h] = Wq[idx];
}

// Mt[a][h] = sum_d W_out[d][h]*ptr_Wq[d][a]; bq[a] = sum_d b_out[d]*ptr_Wq[d][a]
__global__ __launch_bounds__(512)
void k_mt(const float* __restrict__ W_out, const float* __restrict__ ptr_Wq,
          const float* __restrict__ b_out, float* __restrict__ Mt, float* __restrict__ bqv) {
  int a = blockIdx.x, tid = threadIdx.x;
  if (a < 256) {
    float acc = 0.f;
    for (int d = 0; d < 256; ++d) acc = fmaf(W_out[d * 512 + tid], ptr_Wq[d * 256 + a], acc);
    Mt[a * 512 + tid] = acc;
  } else if (tid < 256) {
    float acc = 0.f;
    for (int d = 0; d < 256; ++d) acc = fmaf(b_out[d], ptr_Wq[d * 256 + tid], acc);
    bqv[tid] = acc;
  }
}

// ptr_keys = dense @ ptr_Wk : 16 rows of (b,l) per block
__global__ __launch_bounds__(256)
void k_ptrkeys(const float* __restrict__ dense, const float* __restrict__ Wk,
               float* __restrict__ keys) {
  __shared__ float s[16 * 256];
  int r0 = blockIdx.x * 16, tid = threadIdx.x;
  for (int idx = tid; idx < 16 * 256; idx += 256) s[idx] = dense[r0 * 256 + idx];
  __syncthreads();
  float acc[16];
#pragma unroll
  for (int ri = 0; ri < 16; ++ri) acc[ri] = 0.f;
  for (int d = 0; d < 256; ++d) {
    float w = Wk[d * 256 + tid];
#pragma unroll
    for (int ri = 0; ri < 16; ++ri) acc[ri] = fmaf(s[ri * 256 + d], w, acc[ri]);
  }
#pragma unroll
  for (int ri = 0; ri < 16; ++ri) keys[(r0 + ri) * 256 + tid] = acc[ri];
}

// enc_keys = enc_out @ s2s_Wk : 16 rows per block
__global__ __launch_bounds__(512)
void k_enckeys(const float* __restrict__ enc_out, const float* __restrict__ Wk,
               float* __restrict__ keys) {
  __shared__ float s[16 * 512];
  int r0 = blockIdx.x * 16, tid = threadIdx.x;
  for (int idx = tid; idx < 16 * 512; idx += 512) s[idx] = enc_out[r0 * 512 + idx];
  __syncthreads();
  float acc[16];
#pragma unroll
  for (int ri = 0; ri < 16; ++ri) acc[ri] = 0.f;
  for (int h = 0; h < 512; ++h) {
    float w = Wk[h * 512 + tid];
#pragma unroll
    for (int ri = 0; ri < 16; ++ri) acc[ri] = fmaf(s[ri * 512 + h], w, acc[ri]);
  }
#pragma unroll
  for (int ri = 0; ri < 16; ++ri) keys[(r0 + ri) * 512 + tid] = acc[ri];
}

__global__ __launch_bounds__(256)
void k_copy(const float* __restrict__ src, float* __restrict__ dst) {
  int idx = blockIdx.x * 256 + threadIdx.x;
  if (idx < BB * HH) dst[idx] = src[idx];
}

// ---------------- encoder GRU step ----------------
// grid(8,32): b-tile 16, u-tile 16. 256 thr = 16 b x 8 og(2u) x 2 kp(K=768 halves).
__global__ __launch_bounds__(256)
void k_enc(const float* __restrict__ dense, const float* __restrict__ hin,
           float* __restrict__ hout, const float* __restrict__ Wi,
           const float* __restrict__ Wh, const float* __restrict__ bi,
           const float* __restrict__ bh, const int* __restrict__ lengths,
           float* __restrict__ enc_out, float* __restrict__ h0, int t) {
  __shared__ float xs[16 * 772];          // [h(512)|dense(256)] per b, pad 772
  __shared__ float part[2 * 16 * 8 * 8];
  const int tid = threadIdx.x;
  const int b0 = blockIdx.x * 16, u0 = blockIdx.y * 16;
  for (int idx = tid; idx < 16 * 768; idx += 256) {
    int bl = idx / 768, k = idx - bl * 768;
    xs[bl * 772 + k] = (k < 512) ? hin[(b0 + bl) * 512 + k]
                                 : dense[((b0 + bl) * 64 + t) * 256 + (k - 512)];
  }
  __syncthreads();
  {
    const int b_l = tid & 15, og = (tid >> 4) & 7, kp = tid >> 7;
    const int ua = u0 + og * 2;
    float ar0 = 0, az0 = 0, ain0 = 0, ahn0 = 0, ar1 = 0, az1 = 0, ain1 = 0, ahn1 = 0;
    const float* xr = xs + b_l * 772;
    const int k0 = kp * 384, k1 = k0 + 384;
    const int kA = (k1 < 512) ? k1 : 512;
    // h-part: Wh rows -> r,z merged; n-part separate (h_n)
    for (int k = k0; k < kA; k += 4) {
      float4 xv = *(const float4*)(xr + k);
      float4 w;
      w = *(const float4*)(Wh + (ua) * 512 + k);        ar0  = D4(ar0);
      w = *(const float4*)(Wh + (512 + ua) * 512 + k);  az0  = D4(az0);
      w = *(const float4*)(Wh + (1024 + ua) * 512 + k); ahn0 = D4(ahn0);
      w = *(const float4*)(Wh + (ua + 1) * 512 + k);    ar1  = D4(ar1);
      w = *(const float4*)(Wh + (513 + ua) * 512 + k);  az1  = D4(az1);
      w = *(const float4*)(Wh + (1025 + ua) * 512 + k); ahn1 = D4(ahn1);
    }
    const int kB = (k0 > 512) ? k0 : 512;
    for (int k = kB; k < k1; k += 4) {
      float4 xv = *(const float4*)(xr + k);
      float4 w;
      w = *(const float4*)(Wi + (ua) * 256 + k - 512);        ar0  = D4(ar0);
      w = *(const float4*)(Wi + (512 + ua) * 256 + k - 512);  az0  = D4(az0);
      w = *(const float4*)(Wi + (1024 + ua) * 256 + k - 512); ain0 = D4(ain0);
      w = *(const float4*)(Wi + (ua + 1) * 256 + k - 512);    ar1  = D4(ar1);
      w = *(const float4*)(Wi + (513 + ua) * 256 + k - 512);  az1  = D4(az1);
      w = *(const float4*)(Wi + (1025 + ua) * 256 + k - 512); ain1 = D4(ain1);
    }
    float* pp = part + ((kp * 16 + b_l) * 8 + og) * 8;
    pp[0] = ar0; pp[1] = az0; pp[2] = ain0; pp[3] = ahn0;
    pp[4] = ar1; pp[5] = az1; pp[6] = ain1; pp[7] = ahn1;
  }
  __syncthreads();
  {
    const int b_l = tid & 15, u_l = tid >> 4;
    const int og = u_l >> 1, uu = u_l & 1;
    const float* p0 = part + ((0 * 16 + b_l) * 8 + og) * 8 + uu * 4;
    const float* p1 = part + ((1 * 16 + b_l) * 8 + og) * 8 + uu * 4;
    float ar = p0[0] + p1[0], az = p0[1] + p1[1];
    float ain = p0[2] + p1[2], ahn = p0[3] + p1[3];
    const int u = u0 + u_l, b = b0 + b_l;
    float r = sigmoidf_(ar + bi[u] + bh[u]);
    float z = sigmoidf_(az + bi[512 + u] + bh[512 + u]);
    float n = fast_tanh(ain + bi[1024 + u] + r * (ahn + bh[1024 + u]));
    float hp = xs[b_l * 772 + u];
    float hn = (1.f - z) * n + z * hp;
    hout[b * 512 + u] = hn;
    int lenb = lengths[b];
    enc_out[(b * 64 + t) * 512 + u] = (t < lenb) ? hn : 0.f;
    if (t == lenb - 1) h0[b * 512 + u] = hn;
  }
}

// ---------------- decoder P1: pointer-output(j=step-1) + attention(step) ----------------
__global__ __launch_bounds__(256)
void k_p1(int step, const float* __restrict__ qbuf, const float* __restrict__ pqbuf,
          const float* __restrict__ enc_keys, const float* __restrict__ ptr_keys,
          const float* __restrict__ enc_out, const float* __restrict__ dense,
          const float* __restrict__ s2s_v, const float* __restrict__ ptr_v,
          const int* __restrict__ lengths, const int* __restrict__ targets,
          int* __restrict__ smask, float* __restrict__ xbuf,
          float* __restrict__ logits, float* __restrict__ preds) {
  __shared__ float sq[512], sv[512], sl[64], wl[64];
  const int b = blockIdx.x, tid = threadIdx.x;
  const int wv = tid >> 6, ln = tid & 63;
  const int lenb = lengths[b];
  if (step > 0) {
    const int j = step - 1;
    sq[tid] = pqbuf[b * 256 + (tid & 255)];
    sv[tid] = ptr_v[tid & 255];
    __syncthreads();
#pragma unroll 4
    for (int li = 0; li < 16; ++li) {
      int l = wv * 16 + li;
      float acc = 0.f;
#pragma unroll
      for (int c = 0; c < 4; ++c) {
        int a = c * 64 + ln;
        acc = fmaf(fast_tanh(sq[a] + ptr_keys[(b * 64 + l) * 256 + a]), sv[a], acc);
      }
      acc = wsum(acc);
      if (ln == 0) sl[l] = acc;
    }
    __syncthreads();
    if (tid < 64) {
      int l = tid;
      bool pm = (j < lenb) && (l < lenb) && (smask[b * 64 + l] != 0);
      float v = pm ? sl[l] : NEGC;
      logits[(b * 64 + j) * 64 + l] = v;
      float bv = v; int bidx = l;
#pragma unroll
      for (int off = 32; off > 0; off >>= 1) {
        float ov = __shfl_xor(bv, off);
        int oi = __shfl_xor(bidx, off);
        if (ov > bv || (ov == bv && oi < bidx)) { bv = ov; bidx = oi; }
      }
      if (l == 0) preds[b * 64 + j] = (float)bidx;
    }
    __syncthreads();
    if (tid == 0) smask[b * 64 + targets[b * 64 + j]] = 0;
    __syncthreads();
  }
  if (step < 64) {
    const int i = step;
    sq[tid] = qbuf[b * 512 + tid];
    sq[tid + 256] = qbuf[b * 512 + 256 + tid];
    sv[tid] = s2s_v[tid];
    sv[tid + 256] = s2s_v[256 + tid];
    __syncthreads();
#pragma unroll 2
    for (int li = 0; li < 16; ++li) {
      int l = wv * 16 + li;
      float acc = 0.f;
#pragma unroll
      for (int c = 0; c < 8; ++c) {
        int a = c * 64 + ln;
        acc = fmaf(fast_tanh(sq[a] + enc_keys[(b * 64 + l) * 512 + a]), sv[a], acc);
      }
      acc = wsum(acc);
      if (ln == 0) sl[l] = ((i < lenb) && (l < lenb)) ? acc : NEGC;
    }
    __syncthreads();
    if (tid < 64) {
      float v = sl[tid];
      float m = v;
#pragma unroll
      for (int off = 32; off > 0; off >>= 1) m = fmaxf(m, __shfl_xor(m, off));
      float e = __expf(v - m);
      float s = e;
#pragma unroll
      for (int off = 32; off > 0; off >>= 1) s += __shfl_xor(s, off);
      wl[tid] = e / s;
    }
    __syncthreads();
    for (int hh = tid; hh < 512; hh += 256) {
      float c = 0.f;
#pragma unroll 8
      for (int l = 0; l < 64; ++l) c = fmaf(wl[l], enc_out[(b * 64 + l) * 512 + hh], c);
      xbuf[b * 768 + hh] = c;
    }
    int idx = (i == 0) ? 0 : targets[b * 64 + i - 1];
    xbuf[b * 768 + 512 + tid] = dense[(b * 64 + idx) * 256 + tid];
  }
}

// ---------------- decoder P2: gates GEMM + GRU pointwise -> h_new ----------------
// grid(16,32): b-tile 8, u-tile 16. 256 thr = 8 b x 8 og(2u) x 4 kp(K=1280 quarters).
__global__ __launch_bounds__(256)
void k_p2(const float* __restrict__ xbuf, const float* __restrict__ hin,
          float* __restrict__ hout, const float* __restrict__ Wi,
          const float* __restrict__ Wh, const float* __restrict__ bi,
          const float* __restrict__ bh) {
  __shared__ float xs[8 * 1284];          // [ctx|din|h] per b, pad 1284
  __shared__ float part[4 * 8 * 8 * 8];
  const int tid = threadIdx.x;
  const int b0 = blockIdx.x * 8, u0 = blockIdx.y * 16;
  for (int idx = tid; idx < 8 * 1280; idx += 256) {
    int bl = idx / 1280, k = idx - bl * 1280;
    xs[bl * 1284 + k] = (k < 768) ? xbuf[(b0 + bl) * 768 + k]
                                  : hin[(b0 + bl) * 512 + (k - 768)];
  }
  __syncthreads();
  {
    const int b_l = tid & 7, og = (tid >> 3) & 7, kp = tid >> 6;
    const int ua = u0 + og * 2;
    float ar0 = 0, az0 = 0, ain0 = 0, ahn0 = 0, ar1 = 0, az1 = 0, ain1 = 0, ahn1 = 0;
    const float* xr = xs + b_l * 1284;
    const int k0 = kp * 320, k1 = k0 + 320;
    const int kA = (k1 < 768) ? k1 : 768;
    // i-part (Wi over [ctx|din], K<768): r,z merged; i_n separate
    for (int k = k0; k < kA; k += 4) {
      float4 xv = *(const float4*)(xr + k);
      float4 w;
      w = *(const float4*)(Wi + (ua) * 768 + k);        ar0  = D4(ar0);
      w = *(const float4*)(Wi + (512 + ua) * 768 + k);  az0  = D4(az0);
      w = *(const float4*)(Wi + (1024 + ua) * 768 + k); ain0 = D4(ain0);
      w = *(const float4*)(Wi + (ua + 1) * 768 + k);    ar1  = D4(ar1);
      w = *(const float4*)(Wi + (513 + ua) * 768 + k);  az1  = D4(az1);
      w = *(const float4*)(Wi + (1025 + ua) * 768 + k); ain1 = D4(ain1);
    }
    const int kB = (k0 > 768) ? k0 : 768;
    for (int k = kB; k < k1; k += 4) {
      float4 xv = *(const float4*)(xr + k);
      float4 w;
      w = *(const float4*)(Wh + (ua) * 512 + k - 768);        ar0  = D4(ar0);
      w = *(const float4*)(Wh + (512 + ua) * 512 + k - 768);  az0  = D4(az0);
      w = *(const float4*)(Wh + (1024 + ua) * 512 + k - 768); ahn0 = D4(ahn0);
      w = *(const float4*)(Wh + (ua + 1) * 512 + k - 768);    ar1  = D4(ar1);
      w = *(const float4*)(Wh + (513 + ua) * 512 + k - 768);  az1  = D4(az1);
      w = *(const float4*)(Wh + (1025 + ua) * 512 + k - 768); ahn1 = D4(ahn1);
    }
    float* pp = part + ((kp * 8 + b_l) * 8 + og) * 8;
    pp[0] = ar0; pp[1] = az0; pp[2] = ain0; pp[3] = ahn0;
    pp[4] = ar1; pp[5] = az1; pp[6] = ain1; pp[7] = ahn1;
  }
  __syncthreads();
  if (tid < 128) {
    const int b_l = tid & 7, u_l = tid >> 3;
    const int og = u_l >> 1, uu = u_l & 1;
    float ar = 0, az = 0, ain = 0, ahn = 0;
#pragma unroll
    for (int kp = 0; kp < 4; ++kp) {
      const float* p = part + ((kp * 8 + b_l) * 8 + og) * 8 + uu * 4;
      ar += p[0]; az += p[1]; ain += p[2]; ahn += p[3];
    }
    const int u = u0 + u_l, b = b0 + b_l;
    float r = sigmoidf_(ar + bi[u] + bh[u]);
    float z = sigmoidf_(az + bi[512 + u] + bh[512 + u]);
    float n = fast_tanh(ain + bi[1024 + u] + r * (ahn + bh[1024 + u]));
    float hp = xs[b_l * 1284 + 768 + u];
    hout[b * 512 + u] = (1.f - z) * n + z * hp;
  }
}

// ---------------- decoder P3: [q(512)|pq(256)] = h_new @ [Wqt|Mt]^T ----------------
// grid(8,96): b-tile 16, out-tile 8. 256 thr = 16 b x 2 og(4 out) x 8 kp(K=512).
__global__ __launch_bounds__(256)
void k_p3(const float* __restrict__ hsrc, const float* __restrict__ Wqt,
          const float* __restrict__ Mt, const float* __restrict__ bqv,
          float* __restrict__ qbuf, float* __restrict__ pqbuf) {
  __shared__ float hs[16 * 516];
  __shared__ float part[8 * 16 * 8];
  const int tid = threadIdx.x;
  const int b0 = blockIdx.x * 16, o0 = blockIdx.y * 8;
  for (int idx = tid; idx < 16 * 512; idx += 256) {
    int bl = idx >> 9, k = idx & 511;
    hs[bl * 516 + k] = hsrc[(b0 + bl) * 512 + k];
  }
  __syncthreads();
  {
    const int b_l = tid & 15, og = (tid >> 4) & 1, kp = tid >> 5;
    const int ob = o0 + og * 4;
    const float* w0 = (ob < 512) ? (Wqt + (ob) * 512) : (Mt + (ob - 512) * 512);
    const float* w1 = (ob < 512) ? (Wqt + (ob + 1) * 512) : (Mt + (ob - 511) * 512);
    const float* w2 = (ob < 512) ? (Wqt + (ob + 2) * 512) : (Mt + (ob - 510) * 512);
    const float* w3 = (ob < 512) ? (Wqt + (ob + 3) * 512) : (Mt + (ob - 509) * 512);
    float a0 = 0, a1 = 0, a2 = 0, a3 = 0;
    const float* xr = hs + b_l * 516;
    const int k0 = kp * 64;
    for (int k = k0; k < k0 + 64; k += 4) {
      float4 xv = *(const float4*)(xr + k);
      float4 w;
      w = *(const float4*)(w0 + k); a0 = D4(a0);
      w = *(const float4*)(w1 + k); a1 = D4(a1);
      w = *(const float4*)(w2 + k); a2 = D4(a2);
      w = *(const float4*)(w3 + k); a3 = D4(a3);
    }
    float* pp = part + ((kp * 16 + b_l) * 8 + og * 4);
    pp[0] = a0; pp[1] = a1; pp[2] = a2; pp[3] = a3;
  }
  __syncthreads();
  if (tid < 128) {
    const int b_l = tid & 15, o_l = tid >> 4;
    float s = 0.f;
#pragma unroll
    for (int kp = 0; kp < 8; ++kp) s += part[(kp * 16 + b_l) * 8 + o_l];
    const int b = b0 + b_l, o = o0 + o_l;
    if (o < 512) qbuf[b * 512 + o] = s;
    else pqbuf[b * 256 + (o - 512)] = s + bqv[o - 512];
  }
}

extern "C" void kernel_launch(void* const* d_in, const int* in_sizes, int n_in,
                              void* d_out, int out_size, void* d_ws, size_t ws_size,
                              hipStream_t stream) {
  (void)in_sizes; (void)n_in; (void)out_size; (void)ws_size;
  const float* inputs  = (const float*)d_in[0];
  const int*   lengths = (const int*)d_in[1];
  const int*   targets = (const int*)d_in[2];
  const float* W_in    = (const float*)d_in[3];
  const float* b_in    = (const float*)d_in[4];
  const float* enc_Wi  = (const float*)d_in[5];
  const float* enc_Wh  = (const float*)d_in[6];
  const float* enc_bi  = (const float*)d_in[7];
  const float* enc_bh  = (const float*)d_in[8];
  const float* dec_Wi  = (const float*)d_in[9];
  const float* dec_Wh  = (const float*)d_in[10];
  const float* dec_bi  = (const float*)d_in[11];
  const float* dec_bh  = (const float*)d_in[12];
  const float* s2s_Wq  = (const float*)d_in[13];
  const float* s2s_Wk  = (const float*)d_in[14];
  const float* s2s_v   = (const float*)d_in[15];
  const float* W_out   = (const float*)d_in[16];
  const float* b_out   = (const float*)d_in[17];
  const float* ptr_Wq  = (const float*)d_in[18];
  const float* ptr_Wk  = (const float*)d_in[19];
  const float* ptr_v   = (const float*)d_in[20];

  float* ws = (float*)d_ws;
  float* dense    = ws + OFF_DENSE;
  float* enc_out  = ws + OFF_ENCOUT;
  float* enc_keys = ws + OFF_ENCKEYS;
  float* ptr_keys = ws + OFF_PTRKEYS;
  float* xbuf     = ws + OFF_X;
  float* hb0      = ws + OFF_HB0;
  float* hb1      = ws + OFF_HB1;
  float* h0       = ws + OFF_H0;
  float* qbuf     = ws + OFF_Q;
  float* pqbuf    = ws + OFF_PQ;
  float* Wqt      = ws + OFF_WQT;
  float* Mt       = ws + OFF_MT;
  float* bqv      = ws + OFF_BQ;
  int*   smask    = (int*)(ws + OFF_SMASK);

  float* logits = (float*)d_out;
  float* preds  = (float*)d_out + BB * LL * LL;

  // setup
  k_init<<<8480, 256, 0, stream>>>(inputs, W_in, b_in, dense, hb0, smask);
  k_tr<<<1024, 256, 0, stream>>>(s2s_Wq, Wqt);
  k_mt<<<257, 512, 0, stream>>>(W_out, ptr_Wq, b_out, Mt, bqv);
  k_ptrkeys<<<512, 256, 0, stream>>>(dense, ptr_Wk, ptr_keys);

  // encoder
  for (int t = 0; t < 64; ++t) {
    float* hi = (t & 1) ? hb1 : hb0;
    float* ho = (t & 1) ? hb0 : hb1;
    k_enc<<<dim3(8, 32), 256, 0, stream>>>(dense, hi, ho, enc_Wi, enc_Wh, enc_bi,
                                           enc_bh, lengths, enc_out, h0, t);
  }
  k_copy<<<256, 256, 0, stream>>>(h0, hb0);      // decoder h starts at hidden0
  k_enckeys<<<512, 512, 0, stream>>>(enc_out, s2s_Wk, enc_keys);
  k_p3<<<dim3(8, 96), 256, 0, stream>>>(hb0, Wqt, Mt, bqv, qbuf, pqbuf);  // q for step 0

  // decoder
  for (int i = 0; i < 64; ++i) {
    float* hi = (i & 1) ? hb1 : hb0;
    float* ho = (i & 1) ? hb0 : hb1;
    k_p1<<<128, 256, 0, stream>>>(i, qbuf, pqbuf, enc_keys, ptr_keys, enc_out, dense,
                                  s2s_v, ptr_v, lengths, targets, smask, xbuf,
                                  logits, preds);
    k_p2<<<dim3(16, 32), 256, 0, stream>>>(xbuf, hi, ho, dec_Wi, dec_Wh, dec_bi, dec_bh);
    k_p3<<<dim3(8, 96), 256, 0, stream>>>(ho, Wqt, Mt, bqv, qbuf, pqbuf);
  }
  // emit outputs for last step
  k_p1<<<128, 256, 0, stream>>>(64, qbuf, pqbuf, enc_keys, ptr_keys, enc_out, dense,
                                s2s_v, ptr_v, lengths, targets, smask, xbuf,
                                logits, preds);
}